// Round 12
// baseline (144.969 us; speedup 1.0000x reference)
//
#include <hip/hip_runtime.h>
#include <hip/hip_bf16.h>

// N=32 time, 32x32 grid, C=64 (H=4 x D=16), 3x3x3 offsets (M=27), 2 layers.
// R12: 32x32x16 MFMA (2x MACs/instr). Block = 2 spatial cells x 32 n, 512 thr,
// grid 16x32=512 (exactly 2 blocks/CU). Wave = (cell, chan-half, m-group).
// Biases via MFMA C-operand init (zero VALU bias math). Per-m validity is
// wave-uniform (no ci loop). Keeps R9-verified no-max softmax + bf16 residual.

typedef short short8_t __attribute__((ext_vector_type(8)));
typedef float floatx16 __attribute__((ext_vector_type(16)));

__device__ __forceinline__ short f2bs(float f) {
    __hip_bfloat16 h = __float2bfloat16(f);
    return *reinterpret_cast<short*>(&h);
}
__device__ __forceinline__ float bs2f(short s) {
    union { unsigned u; float f; } v;
    v.u = ((unsigned)(unsigned short)s) << 16;
    return v.f;
}
// swizzled halo addressing: rowid in [0,408), 8 chunks of 8 shorts, pitch 64
__device__ __forceinline__ int hn_idx(int rowid, int chunk) {
    return rowid * 64 + ((chunk ^ (rowid & 7)) << 3);
}
// bias C-fragment: rows (reg&3)+8*(reg>>2)+4*h5 -> 4 float4 at base+{0,8,16,24}
__device__ __forceinline__ floatx16 bias_frag(const float* __restrict__ p) {
    float4 f0 = *(const float4*)(p);
    float4 f1 = *(const float4*)(p + 8);
    float4 f2 = *(const float4*)(p + 16);
    float4 f3 = *(const float4*)(p + 24);
    floatx16 c;
    c[0]=f0.x;  c[1]=f0.y;  c[2]=f0.z;  c[3]=f0.w;
    c[4]=f1.x;  c[5]=f1.y;  c[6]=f1.z;  c[7]=f1.w;
    c[8]=f2.x;  c[9]=f2.y;  c[10]=f2.z; c[11]=f2.w;
    c[12]=f3.x; c[13]=f3.y; c[14]=f3.z; c[15]=f3.w;
    return c;
}

// ---------------- prep: repack weights (32x32 A-frag) + BN partials ----------
// A-frag for chan-half ch: dst[mat][((kk*2+ch)*64+lane)*8+j]
//   = W[kk*16 + (lane>>5)*8 + j][ch*32 + (lane&31)],  kk in [0,4)
__global__ void prep_kernel(const float* __restrict__ Wq, const float* __restrict__ Wk,
                            const float* __restrict__ Wv, short* __restrict__ dst,
                            const float* __restrict__ x, float* __restrict__ sums) {
    if (blockIdx.x < 220) {
        int t = blockIdx.x * 256 + threadIdx.x;
        if (t >= 110 * 512) return;
        int mat  = t >> 9;
        int rem  = t & 511;
        int kk   = rem >> 7;
        int ch   = (rem >> 6) & 1;
        int lane = rem & 63;
        int krow = kk * 16 + (lane >> 5) * 8;
        int col  = ch * 32 + (lane & 31);
        const float* W;
        if (mat < 2)       W = Wq + mat * 4096;
        else if (mat < 56) W = Wk + (mat - 2) * 4096;
        else               W = Wv + (mat - 56) * 4096;
        short8_t v;
        #pragma unroll
        for (int j = 0; j < 8; ++j) v[j] = f2bs(W[(krow + j) * 64 + col]);
        *(short8_t*)&dst[(size_t)mat * 4096 + ((kk * 2 + ch) * 64 + lane) * 8] = v;
    } else {
        int bid = blockIdx.x - 220;
        int t = bid * 256 + threadIdx.x;
        const float4* x4 = (const float4*)x;
        float4 v0 = x4[t * 3 + 0], v1 = x4[t * 3 + 1], v2 = x4[t * 3 + 2];
        float vv[6];
        vv[0] = v0.x + v0.w + v1.z + v2.y;
        vv[1] = v0.y + v1.x + v1.w + v2.z;
        vv[2] = v0.z + v1.y + v2.x + v2.w;
        vv[3] = v0.x*v0.x + v0.w*v0.w + v1.z*v1.z + v2.y*v2.y;
        vv[4] = v0.y*v0.y + v1.x*v1.x + v1.w*v1.w + v2.z*v2.z;
        vv[5] = v0.z*v0.z + v1.y*v1.y + v2.x*v2.x + v2.w*v2.w;
        #pragma unroll
        for (int i = 0; i < 6; ++i) {
            #pragma unroll
            for (int off = 1; off < 64; off <<= 1) vv[i] += __shfl_xor(vv[i], off);
        }
        __shared__ float part[4][6];
        if ((threadIdx.x & 63) == 0) {
            #pragma unroll
            for (int i = 0; i < 6; ++i) part[threadIdx.x >> 6][i] = vv[i];
        }
        __syncthreads();
        if (threadIdx.x < 6)
            sums[bid * 8 + threadIdx.x] = part[0][threadIdx.x] + part[1][threadIdx.x] +
                                          part[2][threadIdx.x] + part[3][threadIdx.x];
    }
}

// ---------------- fused attention layer (32x32x16 MFMA) ----------------
// grid (bx=16, a=32); block 512 = 8 waves: cw=wv&1 (cell), ch=(wv>>1)&1, g2=wv>>2.
// Halo: rowid = (spa*4 + jc)*34 + r; spa in [0,3), jc in [0,4) (cols b0-1..b0+2),
// r = src_n + 1 in [0,34).
template <bool FIRST>
__global__ __launch_bounds__(512, 4)
void layer_fused(const float* __restrict__ x, const float* __restrict__ sums,
                 const float* __restrict__ W_in, const float* __restrict__ b_in,
                 const short* __restrict__ hbf_in, short* __restrict__ hbf_out,
                 const float* __restrict__ Wout, const float* __restrict__ bout,
                 float* __restrict__ out,
                 const short* __restrict__ wqB, const float* __restrict__ bq,
                 const short* __restrict__ wkB, const float* __restrict__ bk,
                 const short* __restrict__ wvB, const float* __restrict__ bv) {
    __shared__ short HnS[408 * 64];   // 51 KB; reused for state merge + hf
    __shared__ float Waux[256];
    __shared__ float bn6[6];

    const int tid = threadIdx.x;
    const int b0  = blockIdx.x * 2;
    const int a   = blockIdx.y;

    if (FIRST) {
        if (tid < 3) {
            float s = 0.f, qq = 0.f;
            #pragma unroll
            for (int p = 0; p < 32; ++p) { s += sums[p * 8 + tid]; qq += sums[p * 8 + 3 + tid]; }
            float mean = s * (1.f / 32768.f);
            float var  = qq * (1.f / 32768.f) - mean * mean;
            bn6[tid]     = mean;
            bn6[3 + tid] = rsqrtf(var + 1e-5f);
        }
        if (tid < 192)      Waux[tid] = W_in[tid];
        else if (tid < 256) Waux[tid] = b_in[tid - 192];
    } else {
        if (tid < 192)      Waux[tid] = Wout[tid];
        else if (tid < 195) Waux[tid] = bout[tid - 192];
    }
    __syncthreads();

    float mean0 = 0, mean1 = 0, mean2 = 0, rs0 = 0, rs1 = 0, rs2 = 0;
    if (FIRST) {
        mean0 = bn6[0]; mean1 = bn6[1]; mean2 = bn6[2];
        rs0 = bn6[3]; rs1 = bn6[4]; rs2 = bn6[5];
    }

    // ---- stage halo: 408 rows x 8 chunks of 8 bf16 ----
    for (int id = tid; id < 3264; id += 512) {
        int rowid = id >> 3, cc = id & 7;
        int rw = (rowid * 241) >> 13;         // rowid/34 for rowid<408
        int r  = rowid - rw * 34;
        int spa = rw >> 2, jc = rw & 3;
        int aa = a + spa - 1, bb = b0 + jc - 1;
        int n  = r - 1;
        short8_t v = {0, 0, 0, 0, 0, 0, 0, 0};
        if ((unsigned)n < 32u && (unsigned)aa < 32u && (unsigned)bb < 32u) {
            int cell = (n * 32 + aa) * 32 + bb;
            if (FIRST) {
                float xn0 = (x[cell*3+0] - mean0) * rs0;
                float xn1 = (x[cell*3+1] - mean1) * rs1;
                float xn2 = (x[cell*3+2] - mean2) * rs2;
                #pragma unroll
                for (int j = 0; j < 8; ++j) {
                    int c = cc * 8 + j;
                    float h = Waux[192+c] + xn0*Waux[c] + xn1*Waux[64+c] + xn2*Waux[128+c];
                    v[j] = f2bs(h);
                }
            } else {
                v = *(const short8_t*)&hbf_in[cell * 64 + cc * 8];
            }
        }
        *(short8_t*)&HnS[hn_idx(rowid, cc)] = v;
    }
    __syncthreads();

    const int lane = tid & 63;
    const int wv8  = tid >> 6;
    const int cw   = wv8 & 1;          // cell (b0+cw)
    const int ch   = (wv8 >> 1) & 1;   // chan-half (heads 2ch, 2ch+1)
    const int g2   = wv8 >> 2;         // m-group
    const int nn   = lane & 31;        // col = time row n
    const int h5   = lane >> 5;
    const int cb4  = ch * 32 + 4 * h5; // bias-frag base

    bool va[3], vvb[3];
    #pragma unroll
    for (int d = 0; d < 3; ++d) {
        va[d]  = (unsigned)(a + d - 1) < 32u;
        vvb[d] = (unsigned)(b0 + cw + d - 1) < 32u;
    }

    // ---- Q^T projection (C-init = bq frag) ----
    floatx16 qc = bias_frag(bq + cb4);
    {
        const int rq = (4 + cw + 1) * 34 + nn + 1;   // spa=1, jc=cw+1
        #pragma unroll
        for (int kk = 0; kk < 4; ++kk) {
            short8_t wf = *(const short8_t*)&wqB[((kk * 2 + ch) * 64 + lane) * 8];
            short8_t bf = *(const short8_t*)&HnS[hn_idx(rq, kk * 2 + h5)];
            qc = __builtin_amdgcn_mfma_f32_32x32x16_bf16(wf, bf, qc, 0, 0, 0);
        }
    }

    // ---- fused K/V pass, no-max softmax ----
    floatx16 o;
    #pragma unroll
    for (int r = 0; r < 16; ++r) o[r] = 0.f;
    float ss0 = 0.f, ss1 = 0.f;

    const int mstart = g2 ? 14 : 0;
    const int mend   = g2 ? 27 : 14;
    for (int m = mstart; m < mend; ++m) {
        const int t  = (m * 57) >> 9;          // m/9
        const int sp = m - 9 * t;
        const int di = (sp * 11) >> 5;         // sp/3
        const int dj = sp - 3 * di;
        if (!va[di] || !vvb[dj]) continue;     // wave-uniform
        const int rowb = (di * 4 + cw + dj) * 34 + nn + t;
        short8_t bfr0 = *(const short8_t*)&HnS[hn_idx(rowb, 0 * 2 + h5)];
        short8_t bfr1 = *(const short8_t*)&HnS[hn_idx(rowb, 1 * 2 + h5)];
        short8_t bfr2 = *(const short8_t*)&HnS[hn_idx(rowb, 2 * 2 + h5)];
        short8_t bfr3 = *(const short8_t*)&HnS[hn_idx(rowb, 3 * 2 + h5)];
        const short* wkp = wkB + m * 4096 + (ch * 64 + lane) * 8;
        const short* wvp = wvB + m * 4096 + (ch * 64 + lane) * 8;
        floatx16 kc = bias_frag(bk + m * 64 + cb4);
        kc = __builtin_amdgcn_mfma_f32_32x32x16_bf16(*(const short8_t*)(wkp),        bfr0, kc, 0, 0, 0);
        kc = __builtin_amdgcn_mfma_f32_32x32x16_bf16(*(const short8_t*)(wkp + 1024), bfr1, kc, 0, 0, 0);
        kc = __builtin_amdgcn_mfma_f32_32x32x16_bf16(*(const short8_t*)(wkp + 2048), bfr2, kc, 0, 0, 0);
        kc = __builtin_amdgcn_mfma_f32_32x32x16_bf16(*(const short8_t*)(wkp + 3072), bfr3, kc, 0, 0, 0);
        floatx16 vc = bias_frag(bv + m * 64 + cb4);
        vc = __builtin_amdgcn_mfma_f32_32x32x16_bf16(*(const short8_t*)(wvp),        bfr0, vc, 0, 0, 0);
        vc = __builtin_amdgcn_mfma_f32_32x32x16_bf16(*(const short8_t*)(wvp + 1024), bfr1, vc, 0, 0, 0);
        vc = __builtin_amdgcn_mfma_f32_32x32x16_bf16(*(const short8_t*)(wvp + 2048), bfr2, vc, 0, 0, 0);
        vc = __builtin_amdgcn_mfma_f32_32x32x16_bf16(*(const short8_t*)(wvp + 3072), bfr3, vc, 0, 0, 0);
        float p0 = 0.f, p1 = 0.f;
        #pragma unroll
        for (int r = 0; r < 8; ++r)  p0 += kc[r] * qc[r];
        #pragma unroll
        for (int r = 8; r < 16; ++r) p1 += kc[r] * qc[r];
        p0 += __shfl_xor(p0, 32);
        p1 += __shfl_xor(p1, 32);
        float w0 = __expf(p0), w1 = __expf(p1);
        ss0 += w0; ss1 += w1;
        #pragma unroll
        for (int r = 0; r < 8; ++r)  o[r] += w0 * vc[r];
        #pragma unroll
        for (int r = 8; r < 16; ++r) o[r] += w1 * vc[r];
    }

    // ---- combine the two m-groups through (dead) halo LDS ----
    __syncthreads();
    float* stbuf = (float*)HnS;            // [(cw*2+ch)*64+lane] * 18 floats
    float* st = &stbuf[((cw * 2 + ch) * 64 + lane) * 18];
    if (g2 == 1) {
        st[0] = ss0; st[1] = ss1;
        #pragma unroll
        for (int r = 0; r < 16; ++r) st[2 + r] = o[r];
    }
    __syncthreads();
    if (g2 == 0) {
        float inv0 = 1.0f / (ss0 + st[0]);
        float inv1 = 1.0f / (ss1 + st[1]);
        #pragma unroll
        for (int r = 0; r < 8; ++r)  o[r] = (o[r] + st[2 + r]) * inv0;
        #pragma unroll
        for (int r = 8; r < 16; ++r) o[r] = (o[r] + st[2 + r]) * inv1;
    }

    // ---- epilogue (g2==0 waves own outputs): lane = (col n, 16 chans) ----
    const int cell = (nn * 32 + a) * 32 + b0 + cw;
    if (FIRST) {
        if (g2 == 0) {
            float xn0 = (x[cell*3+0] - mean0) * rs0;
            float xn1 = (x[cell*3+1] - mean1) * rs1;
            float xn2 = (x[cell*3+2] - mean2) * rs2;
            #pragma unroll
            for (int rg = 0; rg < 4; ++rg) {
                int base = ch * 32 + 4 * h5 + 8 * rg;   // 4 contiguous chans
                short4 hb; short* hbp = (short*)&hb;
                #pragma unroll
                for (int i = 0; i < 4; ++i) {
                    int c = base + i;
                    float res = Waux[192+c] + xn0*Waux[c] + xn1*Waux[64+c] + xn2*Waux[128+c];
                    hbp[i] = f2bs(o[rg * 4 + i] + res);
                }
                *(short4*)&hbf_out[cell * 64 + base] = hb;
            }
        }
    } else {
        float resv[16];
        if (g2 == 0) {
            #pragma unroll
            for (int rg = 0; rg < 4; ++rg) {
                int base = ch * 32 + 4 * h5 + 8 * rg;
                short4 hb = *(const short4*)&hbf_in[cell * 64 + base];
                resv[rg*4+0] = bs2f(hb.x); resv[rg*4+1] = bs2f(hb.y);
                resv[rg*4+2] = bs2f(hb.z); resv[rg*4+3] = bs2f(hb.w);
            }
        }
        __syncthreads();                   // stbuf reads done; reuse LDS for hf
        float* hf = (float*)HnS;           // [2 cells][32 n][pitch 68]
        if (g2 == 0) {
            #pragma unroll
            for (int rg = 0; rg < 4; ++rg) {
                int base = ch * 32 + 4 * h5 + 8 * rg;
                float4 d;
                d.x = o[rg*4+0] + resv[rg*4+0];
                d.y = o[rg*4+1] + resv[rg*4+1];
                d.z = o[rg*4+2] + resv[rg*4+2];
                d.w = o[rg*4+3] + resv[rg*4+3];
                *(float4*)&hf[(cw * 32 + nn) * 68 + base] = d;
            }
        }
        __syncthreads();
        if (tid < 192) {
            int rowglob = tid / 3, f = tid - rowglob * 3;   // rowglob = cw*32 + n
            int cw2 = rowglob >> 5, n2 = rowglob & 31;
            float acc = Waux[192 + f];
            #pragma unroll 8
            for (int cc = 0; cc < 64; ++cc) acc += hf[rowglob * 68 + cc] * Waux[cc * 3 + f];
            out[((n2 * 32 + a) * 32 + b0 + cw2) * 3 + f] = acc;
        }
    }
}

extern "C" void kernel_launch(void* const* d_in, const int* in_sizes, int n_in,
                              void* d_out, int out_size, void* d_ws, size_t ws_size,
                              hipStream_t stream) {
    const float* x     = (const float*)d_in[0];
    const float* W_in  = (const float*)d_in[1];
    const float* b_in  = (const float*)d_in[2];
    const float* W_out = (const float*)d_in[3];
    const float* b_out = (const float*)d_in[4];
    const float* Wq    = (const float*)d_in[5];
    const float* bq    = (const float*)d_in[6];
    const float* Wk    = (const float*)d_in[7];
    const float* bk    = (const float*)d_in[8];
    const float* Wv    = (const float*)d_in[9];
    const float* bv    = (const float*)d_in[10];

    float* ws    = (float*)d_ws;
    float* sums  = ws;                          // 32 x 8 floats (BN partials)
    short* h1bf  = (short*)(ws + 256);          // 2M shorts (4 MB)
    short* wB    = h1bf + 2097152;              // 110 x 4096 bf16 (0.9 MB)
    float* out   = (float*)d_out;

    prep_kernel<<<252, 256, 0, stream>>>(Wq, Wk, Wv, wB, x, sums);

    const short* wq0 = wB;                const short* wq1 = wB + 4096;
    const short* wk0 = wB + 2 * 4096;     const short* wk1 = wB + (2 + 27) * 4096;
    const short* wv0 = wB + 56 * 4096;    const short* wv1 = wB + (56 + 27) * 4096;

    dim3 grid(16, 32);
    layer_fused<true><<<grid, 512, 0, stream>>>(
        x, sums, W_in, b_in, nullptr, h1bf, nullptr, nullptr, nullptr,
        wq0, bq, wk0, bk, wv0, bv);
    layer_fused<false><<<grid, 512, 0, stream>>>(
        nullptr, nullptr, nullptr, nullptr, h1bf, nullptr, W_out, b_out, out,
        wq1, bq + 64, wk1, bk + 1728, wv1, bv + 1728);
}